// Round 4
// baseline (250.225 us; speedup 1.0000x reference)
//
#include <hip/hip_runtime.h>

// CTC loss forward (log-space). logits (T,N,C) fp32 log-probs, labels (N,S)
// int32 in [1,C), prediction/target sizes (N,).
//
// One 64-lane wave per batch item n. Lane i owns extended-lattice positions
// 2i (blank) and 2i+1 (label i); cross-lane dep per step = one DPP wave_shr1.
//
// Memory pipeline lives in LDS, not registers (R2/R3 post-mortem: the
// register allocator sinks register prefetches to their uses — VGPR_Count
// stayed 24/32 — leaving one full HBM latency per serial step).
// global_load_lds has NO destination VGPR, so the scheduler cannot collapse
// it: per t-row, one size-4 instruction gathers blank+48 label emissions
// (lane j loads lp[t][n][glab_j], HW scatters to slot+lane*4). A 64-row ring
// (16 KB LDS) keeps 64 rows in flight per wave; consumption is gated by
// constant-immediate `s_waitcnt vmcnt(56)` per 4-step group (never 0).
// Single wave per block -> no __syncthreads -> no compiler vmcnt(0) drains.

constexpr int T = 512, N = 256, C = 256, S = 48;
constexpr int R = 64;                  // ring depth (rows in flight)
constexpr int G = 4;                   // steps per group (unrolled)
#define NEGF (-1e30f)

__device__ __forceinline__ float lae2(float x, float y) {
  float m = fmaxf(x, y);
  float d = fminf(x, y) - m;           // <= 0; exp underflows cleanly for NEG
  return m + __logf(1.0f + __expf(d));
}

__device__ __forceinline__ float lae3(float x, float y, float z) {
  float m = fmaxf(fmaxf(x, y), z);
  float s = __expf(x - m) + __expf(y - m) + __expf(z - m);
  return m + __logf(s);
}

// lane i <- lane i-1, lane 0 <- fill (DPP wave_shr1, ctrl 0x138)
__device__ __forceinline__ float wave_shr1(float v, float fill) {
  int r = __builtin_amdgcn_update_dpp(__float_as_int(fill), __float_as_int(v),
                                      0x138, 0xf, 0xf, false);
  return __int_as_float(r);
}

// async global->LDS: per-lane 4B load, HW scatters to ldsbase + lane*4
__device__ __forceinline__ void gload_lds(const float* g, float* l) {
  __builtin_amdgcn_global_load_lds(
      (const __attribute__((address_space(1))) unsigned int*)g,
      (__attribute__((address_space(3))) unsigned int*)l, 4, 0, 0);
}

__launch_bounds__(64, 1)
__global__ void ctc_alpha_kernel(const float* __restrict__ lp,
                                 const int*  __restrict__ labels,
                                 const int*  __restrict__ in_len,
                                 const int*  __restrict__ tgt_len,
                                 float* __restrict__ loss_ws) {
  // ring slots 0..R-1 (64 floats each), slot R = junk target for clamped
  // issues, +64 pad so lane 63's (masked) ds_read of slot R stays in bounds.
  __shared__ float sh[(R + 2) * 64];

  const int n    = blockIdx.x;
  const int lane = threadIdx.x;

  // compute-side label (lane i owns label i) and gather-side label
  // (lane j stages labels[j-1] at slot offset j; lane 0 stages blank).
  const int lab  = (lane < S) ? labels[n * S + lane] : 0;
  const int glab = (lane >= 1 && lane <= S) ? labels[n * S + lane - 1] : 0;
  const int lab_prev = __shfl_up(lab, 1);
  const bool skip   = (lab != 0) && ((lane == 0) || (lab != lab_prev));
  const bool valid0 = (2 * lane     <= 2 * S);
  const bool valid1 = (2 * lane + 1 <= 2 * S);
  const int Tin = in_len[n];
  const int tl  = tgt_len[n];

  const size_t stride = (size_t)N * C;           // row stride over t
  const float* base = lp + (size_t)n * C;        // lp[0][n][:]

  float a0 = NEGF, a1 = NEGF;
  if (lane == 0) { a0 = base[0]; a1 = base[lab]; }

  // issue one staging load for row `row` (uniform); clamped rows go to the
  // junk slot so every call is exactly one vmem instruction (vmcnt bookkeeping
  // stays a compile-time constant).
  auto issue = [&](int row) {
    const bool ok  = (row < T);
    const int slot = ok ? (row & (R - 1)) : R;
    const int rr   = ok ? row : (T - 1);
    gload_lds(base + (size_t)rr * stride + glab, &sh[slot * 64]);
  };

  auto step = [&](int t, float lpb, float lpl) {
    float a1p = wave_shr1(a1, NEGF);
    float na0 = lae2(a0, a1p) + lpb;                               // blank
    float na1 = (skip ? lae3(a1, a0, a1p) : lae2(a1, a0)) + lpl;   // label
    na0 = valid0 ? na0 : NEGF;
    na1 = valid1 ? na1 : NEGF;
    const bool live = (t < Tin);                  // freeze past input length
    a0 = live ? na0 : a0;
    a1 = live ? na1 : a1;
  };

  // Prologue: fill the ring (rows 1..R in flight).
#pragma unroll
  for (int r = 1; r <= R; ++r) issue(r);

  // Wait for the 4 oldest (rows 1..4), prime the register group.
  asm volatile("s_waitcnt vmcnt(60)" ::: "memory");
  float cb[G], cl[G];
#pragma unroll
  for (int d = 0; d < G; ++d) {
    const int s = (1 + d) & (R - 1);
    cb[d] = sh[s * 64];
    cl[d] = sh[s * 64 + 1 + lane];
  }

  // 127 groups: t0 = 1,5,...,505 -> computes t = 1..508.
  int t0 = 1;
#pragma unroll 1
  for (int grp = 0; grp < 127; ++grp, t0 += G) {
    // rows <= t0+2G-1 complete (issued through t0+R-1; keep 56 newest open)
    asm volatile("s_waitcnt vmcnt(56)" ::: "memory");
    float nb[G], nl[G];
#pragma unroll
    for (int d = 0; d < G; ++d) {                 // prefetch next group's rows
      int pr = t0 + G + d; pr = (pr < T) ? pr : (T - 1);
      const int s = pr & (R - 1);
      nb[d] = sh[s * 64];
      nl[d] = sh[s * 64 + 1 + lane];
    }
#pragma unroll
    for (int d = 0; d < G; ++d) step(t0 + d, cb[d], cl[d]);
#pragma unroll
    for (int d = 0; d < G; ++d) issue(t0 + R + d);
#pragma unroll
    for (int d = 0; d < G; ++d) { cb[d] = nb[d]; cl[d] = nl[d]; }
  }
  // Epilogue: t = 509..511 from the last prefetched group.
#pragma unroll
  for (int d = 0; d < 3; ++d) step(509 + d, cb[d], cl[d]);

  // tails: alpha[2*tl-1] (lane tl-1, odd slot), alpha[2*tl] (lane tl, even)
  const float tail1 = __shfl(a1, tl - 1);
  const float tail2 = __shfl(a0, tl);
  if (lane == 0) {
    float loss = -lae2(tail1, tail2);
    if (!(loss <= 1e29f)) loss = 0.0f;           // zero_infinity (catches NaN)
    loss_ws[n] = loss / (float)tl;
  }
}

__launch_bounds__(256)
__global__ void ctc_reduce_kernel(const float* __restrict__ loss_ws,
                                  float* __restrict__ out) {
  const int tid = threadIdx.x;
  float v = loss_ws[tid];
#pragma unroll
  for (int off = 32; off > 0; off >>= 1) v += __shfl_down(v, off);
  __shared__ float partial[4];
  if ((tid & 63) == 0) partial[tid >> 6] = v;
  __syncthreads();
  if (tid == 0) {
    float s = (partial[0] + partial[1] + partial[2] + partial[3]) / (float)N;
    if (isnan(s) || isinf(s)) s = 0.0f;          // final sanitize()
    out[0] = s;
  }
}

extern "C" void kernel_launch(void* const* d_in, const int* in_sizes, int n_in,
                              void* d_out, int out_size, void* d_ws, size_t ws_size,
                              hipStream_t stream) {
  const float* lp     = (const float*)d_in[0];   // (T, N, C) fp32
  const int*   labels = (const int*)d_in[1];     // (N, S)
  const int*   plen   = (const int*)d_in[2];     // (N,)
  const int*   tlen   = (const int*)d_in[3];     // (N,)
  float* ws  = (float*)d_ws;                     // N floats of scratch
  float* out = (float*)d_out;                    // scalar

  ctc_alpha_kernel<<<N, 64, 0, stream>>>(lp, labels, plen, tlen, ws);
  ctc_reduce_kernel<<<1, 256, 0, stream>>>(ws, out);
}

// Round 5
// 212.003 us; speedup vs baseline: 1.1803x; 1.1803x over previous
//
#include <hip/hip_runtime.h>

// CTC loss forward. logits (T,N,C) fp32 log-probs, labels (N,S) int32 in
// [1,C), prediction/target sizes (N,).
//
// One 64-lane wave per batch item n; lane i owns extended-lattice positions
// 2i (blank) and 2i+1 (label i); cross-lane dep per step = one DPP wave_shr1.
//
// R4 post-mortem: LDS ring pipeline materialized, yet 107 us unchanged and
// L3-resident replays (hbm_bytes=8KB) run at the same speed -> the limit is
// the per-step DEPENDENT CHAIN, which ran through ~6 transcendentals
// (exp/log in logaddexp). R5 removes them: alpha is tracked in LINEAR space
// (add/fma/mul chain only), with a wave-uniform renormalization every 8
// steps (DPP-max butterfly + rcp, logged into `logscale`). Emissions are
// exp()'d in the off-chain prefetch path, pre-boosted by e^+4 per step to
// keep fp32 range; position-validity masking is folded into emissions
// (p=0), costing zero chain ops.

constexpr int T = 512, N = 256, C = 256, S = 48;
constexpr int R = 64;                  // ring rows in flight
constexpr int G = 8;                   // steps per group
constexpr float BOOST = 4.0f;          // per-live-step emission boost (e^4)
static_assert((T - 1) == 63 * G + 7, "schedule hardcodes 63 groups + 7 epilogue");

__device__ __forceinline__ float wave_shr1(float v, float fill) {
  int r = __builtin_amdgcn_update_dpp(__float_as_int(fill), __float_as_int(v),
                                      0x138, 0xf, 0xf, false);  // wave_shr1
  return __int_as_float(r);
}

#define DPP_MAX(v, ctrl)                                                     \
  fmaxf(v, __int_as_float(__builtin_amdgcn_update_dpp(                       \
               __float_as_int(v), __float_as_int(v), (ctrl), 0xf, 0xf, false)))

// max over all 64 lanes, result wave-uniform (via SGPR). alpha >= 0 so the
// old-value fallback on masked/OOB lanes (fmax(v,v)) is always safe.
__device__ __forceinline__ float wavemax(float v) {
  v = DPP_MAX(v, 0x111);               // row_shr:1
  v = DPP_MAX(v, 0x112);               // row_shr:2
  v = DPP_MAX(v, 0x114);               // row_shr:4
  v = DPP_MAX(v, 0x118);               // row_shr:8  -> lane15+16k has row max
  v = DPP_MAX(v, 0x142);               // row_bcast:15
  v = DPP_MAX(v, 0x143);               // row_bcast:31 -> lane 63 has full max
  return __int_as_float(__builtin_amdgcn_readlane(__float_as_int(v), 63));
}

// async global->LDS: per-lane 4B load, HW scatters to ldsbase + lane*4
__device__ __forceinline__ void gload_lds(const float* g, float* l) {
  __builtin_amdgcn_global_load_lds(
      (const __attribute__((address_space(1))) unsigned int*)g,
      (__attribute__((address_space(3))) unsigned int*)l, 4, 0, 0);
}

__launch_bounds__(64, 1)
__global__ void ctc_alpha_kernel(const float* __restrict__ lp,
                                 const int*  __restrict__ labels,
                                 const int*  __restrict__ in_len,
                                 const int*  __restrict__ tgt_len,
                                 float* __restrict__ loss_ws) {
  // ring slots 0..R-1 (64 floats each), slot R = junk target for clamped
  // issues, +pad for lane63's (masked) read of slot base + 64.
  __shared__ float sh[(R + 2) * 64];

  const int n    = blockIdx.x;
  const int lane = threadIdx.x;

  const int lab  = (lane < S) ? labels[n * S + lane] : 0;       // compute side
  const int glab = (lane >= 1 && lane <= S) ? labels[n * S + lane - 1] : 0;
  const int lab_prev = __shfl_up(lab, 1);
  const bool skip   = (lab != 0) && ((lane == 0) || (lab != lab_prev));
  const float skipf = skip ? 1.0f : 0.0f;
  const bool valid0 = (lane <= S);     // pos 2i     in [0, 2S]
  const bool valid1 = (lane <  S);     // pos 2i + 1 in [0, 2S]
  const int Tin = in_len[n];
  const int tl  = tgt_len[n];

  const size_t stride = (size_t)N * C;           // row stride over t
  const float* base = lp + (size_t)n * C;        // lp[0][n][:]

  // alpha0 in linear space (no boost on t=0): only lane 0 live.
  float a0 = (lane == 0) ? __expf(base[0])   : 0.0f;
  float a1 = (lane == 0) ? __expf(base[lab]) : 0.0f;

  auto issue = [&](int row) {          // one vmem inst per call, always
    const bool ok  = (row < T);
    const int slot = ok ? (row & (R - 1)) : R;
    const int rr   = ok ? row : (T - 1);
    gload_lds(base + (size_t)rr * stride + glab, &sh[slot * 64]);
  };

  // Prologue: fill the ring (rows 1..R in flight).
#pragma unroll
  for (int r = 1; r <= R; ++r) issue(r);

  float logscale = 0.0f;

  // rows 1..8 resident; prime current-group emissions (exp'd + masked).
  asm volatile("s_waitcnt vmcnt(56)" ::: "memory");
  float cb[G], cl[G];
#pragma unroll
  for (int d = 0; d < G; ++d) {
    const int s = (1 + d) & (R - 1);
    const float b = sh[s * 64], l = sh[s * 64 + 1 + lane];
    cb[d] = valid0 ? __expf(b + BOOST) : 0.0f;
    cl[d] = valid1 ? __expf(l + BOOST) : 0.0f;
  }

  int t0 = 1;
#pragma unroll 1
  for (int grp = 0; grp < 63; ++grp, t0 += G) {
    // rows <= t0+15 resident (issued through t0+63; keep 48 newest open)
    asm volatile("s_waitcnt vmcnt(48)" ::: "memory");
    float nb[G], nl[G];
#pragma unroll
    for (int d = 0; d < G; ++d) {      // next group's emissions, off-chain
      int pr = t0 + G + d; pr = (pr < T) ? pr : (T - 1);
      const int s = pr & (R - 1);
      const float b = sh[s * 64], l = sh[s * 64 + 1 + lane];
      nb[d] = valid0 ? __expf(b + BOOST) : 0.0f;
      nl[d] = valid1 ? __expf(l + BOOST) : 0.0f;
    }
    if (t0 + G <= Tin) {               // fast path: all 8 steps live
#pragma unroll
      for (int d = 0; d < G; ++d) {
        const float a1p = wave_shr1(a1, 0.0f);
        const float u   = a1 + a0;                 // independent of DPP
        const float na0 = (a0 + a1p) * cb[d];
        const float na1 = fmaf(a1p, skipf, u) * cl[d];
        a0 = na0; a1 = na1;
      }
    } else {                           // tail: wave-uniform freeze check
#pragma unroll
      for (int d = 0; d < G; ++d) {
        const float a1p = wave_shr1(a1, 0.0f);
        const float u   = a1 + a0;
        const float na0 = (a0 + a1p) * cb[d];
        const float na1 = fmaf(a1p, skipf, u) * cl[d];
        if (t0 + d < Tin) { a0 = na0; a1 = na1; }
      }
    }
    // renorm (identity transform + accounting; commutes with freeze)
    float m = fmaxf(wavemax(fmaxf(a0, a1)), 1e-37f);
    const float inv = __builtin_amdgcn_rcpf(m);
    a0 *= inv; a1 *= inv;
    logscale -= __logf(inv);           // log exactly what we applied

#pragma unroll
    for (int d = 0; d < G; ++d) issue(t0 + R + d);
#pragma unroll
    for (int d = 0; d < G; ++d) { cb[d] = nb[d]; cl[d] = nl[d]; }
  }

  // Epilogue: t = 505..511 (cb holds rows 505..512-clamped).
#pragma unroll
  for (int d = 0; d < 7; ++d) {
    const int t = t0 + d;
    const float a1p = wave_shr1(a1, 0.0f);
    const float u   = a1 + a0;
    const float na0 = (a0 + a1p) * cb[d];
    const float na1 = fmaf(a1p, skipf, u) * cl[d];
    if (t < Tin) { a0 = na0; a1 = na1; }
  }

  // tails: alpha[2*tl-1] (lane tl-1, odd slot), alpha[2*tl] (lane tl, even)
  const float tail1 = __shfl(a1, tl - 1);
  const float tail2 = __shfl(a0, tl);
  if (lane == 0) {
    const int live = ((Tin < T) ? Tin : T) - 1;    // boosted live steps
    float loss = -(__logf(tail1 + tail2) + logscale - BOOST * (float)live);
    if (!(loss <= 1e29f) || isnan(loss)) loss = 0.0f;  // zero_infinity
    loss_ws[n] = loss / (float)tl;
  }
}

__launch_bounds__(256)
__global__ void ctc_reduce_kernel(const float* __restrict__ loss_ws,
                                  float* __restrict__ out) {
  const int tid = threadIdx.x;
  float v = loss_ws[tid];
#pragma unroll
  for (int off = 32; off > 0; off >>= 1) v += __shfl_down(v, off);
  __shared__ float partial[4];
  if ((tid & 63) == 0) partial[tid >> 6] = v;
  __syncthreads();
  if (tid == 0) {
    float s = (partial[0] + partial[1] + partial[2] + partial[3]) / (float)N;
    if (isnan(s) || isinf(s)) s = 0.0f;            // final sanitize()
    out[0] = s;
  }
}

extern "C" void kernel_launch(void* const* d_in, const int* in_sizes, int n_in,
                              void* d_out, int out_size, void* d_ws, size_t ws_size,
                              hipStream_t stream) {
  const float* lp     = (const float*)d_in[0];     // (T, N, C) fp32
  const int*   labels = (const int*)d_in[1];       // (N, S)
  const int*   plen   = (const int*)d_in[2];       // (N,)
  const int*   tlen   = (const int*)d_in[3];       // (N,)
  float* ws  = (float*)d_ws;                       // N floats of scratch
  float* out = (float*)d_out;                      // scalar

  ctc_alpha_kernel<<<N, 64, 0, stream>>>(lp, labels, plen, tlen, ws);
  ctc_reduce_kernel<<<1, 256, 0, stream>>>(ws, out);
}